// Round 5
// baseline (523.061 us; speedup 1.0000x reference)
//
#include <hip/hip_runtime.h>
#include <cstdint>

#define HDIM 64
#define BLK  256

// Force a scalar (SMEM) load: addrspace(4) == AMDGPU constant AS. Wave-uniform
// address + constant AS => s_load on the scalar/lgkm pipe (off LDS and VMEM).
// Guard is INSIDE the body so the host semantic pass sees a plain load.
// NOTE: only ever applied to d_in buffers (restored with identical bytes each
// call) -- never to d_ws/d_out, where stale scalar/L2 lines across graph
// replays produced R4's divergence.
__device__ __forceinline__ float ld_s(const float* p) {
#if defined(__HIP_DEVICE_COMPILE__)
    return *(const __attribute__((address_space(4))) float*)(uintptr_t)p;
#else
    return *p;
#endif
}

// tanh(x) = 1 - 2/(exp(2x)+1); exp2/rcp are ~1 ulp -> abs err ~1e-7.
__device__ __forceinline__ float tanh_fast(float v) {
    float e = __builtin_amdgcn_exp2f(v * 2.8853900817779268f);
    float r = __builtin_amdgcn_rcpf(e + 1.0f);
    return fmaf(-2.0f, r, 1.0f);
}

// One thread = one point; single kernel, no workspace.
// Inner (h,k): 5 VALU ops, all weight operands via s_load from d_in.
__global__ __launch_bounds__(BLK) void curl_kernel(
    const float* __restrict__ x,  const float* __restrict__ W1,
    const float* __restrict__ b1, const float* __restrict__ W2,
    const float* __restrict__ b2, const float* __restrict__ W3,
    float* __restrict__ out, int npts)
{
    const int n = blockIdx.x * BLK + threadIdx.x;
    if (n >= npts) return;

    const float x0 = x[n * 3 + 0];
    const float x1 = x[n * 3 + 1];
    const float x2 = x[n * 3 + 2];

    // Layer 1: h1 = tanh(W1 x + b1); D1 = 1 - h1^2 (all in VGPRs, static idx).
    float h1a[HDIM], d1a[HDIM];
#pragma unroll
    for (int i = 0; i < HDIM; ++i) {
        float a = fmaf(ld_s(&W1[i * 3 + 0]), x0, ld_s(&b1[i]));
        a = fmaf(ld_s(&W1[i * 3 + 1]), x1, a);
        a = fmaf(ld_s(&W1[i * 3 + 2]), x2, a);
        const float th = tanh_fast(a);
        h1a[i] = th;
        d1a[i] = fmaf(-th, th, 1.0f);
    }

    // Layer 2 + Jacobian + curl, fused over h:
    //   s0  = b2[h] + sum_k W2[h,k]*h1[k]
    //   u_d = sum_k (W2[h,k]*D1[k]) * W1[k,d]
    //   curl += eps-contraction of (W3[:,h]*D2[h]) with u
    float c0 = 0.f, c1 = 0.f, c2 = 0.f;
    float hb  = ld_s(&b2[0]);
    float w30 = ld_s(&W3[0 * HDIM + 0]);
    float w31 = ld_s(&W3[1 * HDIM + 0]);
    float w32 = ld_s(&W3[2 * HDIM + 0]);
#pragma unroll 1
    for (int h = 0; h < HDIM; ++h) {
        // prefetch next row's epilogue scalars under the k-loop
        float hb_n = 0.f, w30_n = 0.f, w31_n = 0.f, w32_n = 0.f;
        if (h + 1 < HDIM) {
            hb_n  = ld_s(&b2[h + 1]);
            w30_n = ld_s(&W3[0 * HDIM + h + 1]);
            w31_n = ld_s(&W3[1 * HDIM + h + 1]);
            w32_n = ld_s(&W3[2 * HDIM + h + 1]);
        }

        float s0 = hb, u0 = 0.f, u1 = 0.f, u2 = 0.f;
#pragma unroll
        for (int k = 0; k < HDIM; ++k) {
            const float w2 = ld_s(&W2[h * HDIM + k]);   // s_load (uniform)
            s0 = fmaf(w2, h1a[k], s0);
            const float t = w2 * d1a[k];
            u0 = fmaf(t, ld_s(&W1[k * 3 + 0]), u0);     // sL1K-hot after h=0
            u1 = fmaf(t, ld_s(&W1[k * 3 + 1]), u1);
            u2 = fmaf(t, ld_s(&W1[k * 3 + 2]), u2);
        }

        const float th = tanh_fast(s0);
        const float d2 = fmaf(-th, th, 1.0f);
        const float e0 = w30 * d2;
        const float e1 = w31 * d2;
        const float e2 = w32 * d2;
        // curl0 += J21 - J12 ; curl1 += J02 - J20 ; curl2 += J10 - J01
        c0 = fmaf(e2, u1, c0); c0 = fmaf(-e1, u2, c0);
        c1 = fmaf(e0, u2, c1); c1 = fmaf(-e2, u0, c1);
        c2 = fmaf(e1, u0, c2); c2 = fmaf(-e0, u1, c2);

        hb = hb_n; w30 = w30_n; w31 = w31_n; w32 = w32_n;
    }

    out[n * 3 + 0] = c0;
    out[n * 3 + 1] = c1;
    out[n * 3 + 2] = c2;
}

extern "C" void kernel_launch(void* const* d_in, const int* in_sizes, int n_in,
                              void* d_out, int out_size, void* d_ws, size_t ws_size,
                              hipStream_t stream) {
    const float* x  = (const float*)d_in[0];
    const float* W1 = (const float*)d_in[1];
    const float* b1 = (const float*)d_in[2];
    const float* W2 = (const float*)d_in[3];
    const float* b2 = (const float*)d_in[4];
    const float* W3 = (const float*)d_in[5];
    // d_in[6] (b3) unused: constant offset vanishes in the Jacobian.
    float* out = (float*)d_out;

    const int npts = in_sizes[0] / 3;
    const int grid = (npts + BLK - 1) / BLK;
    hipLaunchKernelGGL(curl_kernel, dim3(grid), dim3(BLK), 0, stream,
                       x, W1, b1, W2, b2, W3, out, npts);
}